// Round 1
// baseline (336.795 us; speedup 1.0000x reference)
//
#include <hip/hip_runtime.h>

#define BB 16
#define TT 8192
#define NN 128                     // N_PRE == N_POST
constexpr int CHUNK = 256;         // time-steps per block
constexpr int SUB   = 64;          // time-steps per LDS sub-chunk
constexpr int NBLK  = BB * TT / CHUNK;   // 512 blocks
constexpr int OUTN  = NN * NN;           // 16384

typedef _Float16 f16x8 __attribute__((ext_vector_type(8)));
typedef _Float16 f16x2 __attribute__((ext_vector_type(2)));
typedef float    f32x4 __attribute__((ext_vector_type(4)));

static_assert(CHUNK % SUB == 0, "chunk/sub mismatch");

__device__ __forceinline__ unsigned short h16(float x) {
    _Float16 h = (_Float16)x;
    return __builtin_bit_cast(unsigned short, h);
}

__device__ __forceinline__ float2 ldP2(const float* __restrict__ pb, int t, int q) {
    float2 v = make_float2(0.f, 0.f);
    if (t < TT) v = *(const float2*)(pb + (size_t)t * NN + q);
    return v;
}

// grid 512 x 256 threads. Each block: one 256-step chunk of one batch.
// Computes partial S[p,q] = sum_t pre[t,p]*g[t,q], g = exp-filtered future post,
// plus per-block post column sums (window (t0, t0+256], +row t0 when chunk==0).
template<bool ATOMIC>
__global__ __launch_bounds__(256, 2)
void stdp_main(const float* __restrict__ pre, const float* __restrict__ post,
               const int* __restrict__ dtp,
               _Float16* __restrict__ part, float* __restrict__ wpost,
               float* __restrict__ outat)
{
    __shared__ __align__(16) unsigned short g_lds[NN * 72]; // [q][72] f16, 144B rows
    __shared__ float lds_ps[4][NN];

    const int tid   = threadIdx.x;
    const int blk   = blockIdx.x;
    const int b     = blk >> 5;          // 16 batches
    const int chunk = blk & 31;          // 32 chunks per batch
    const int t0    = chunk * CHUNK;
    const int wv    = tid >> 6;          // wave 0..3
    const int lane  = tid & 63;

    const float dtf = (float)(*dtp);
    const float r   = expf(-dtf * (1.0f / 20.0f));

    const float* pb = post + (size_t)b * TT * NN;
    const float* ab = pre  + (size_t)b * TT * NN;

    const int q0 = lane * 2;             // filter q-pair owned by this lane
    float psx = 0.f, psy = 0.f;          // post sums (exact small ints in fp32)

    f32x4 acc[2][8];
    #pragma unroll
    for (int i = 0; i < 2; ++i)
        #pragma unroll
        for (int j = 0; j < 8; ++j)
            acc[i][j] = (f32x4){0.f, 0.f, 0.f, 0.f};

    for (int sc = 0; sc < CHUNK / SUB; ++sc) {
        const int tc = t0 + sc * SUB;
        // ---------- filter phase: wave wv fills columns [wv*16, wv*16+16) ----------
        {
            const int ts  = tc + wv * 16;
            const int thi = ts + 15;
            unsigned int pk0[8], pk1[8];
            // direct 59-tap init of g[thi]; tau==1 load also feeds post-sum
            float2 p  = ldP2(pb, thi + 1, q0);
            float wt  = r;
            float gx = r * p.x, gy = r * p.y;
            psx += p.x; psy += p.y;
            for (int tau = 2; tau <= 59; ++tau) {
                wt *= r;
                p = ldP2(pb, thi + tau, q0);
                gx = fmaf(wt, p.x, gx);
                gy = fmaf(wt, p.y, gy);
            }
            const float r60 = wt * r;    // r^60, consistent with the chained weights
            pk0[7] = (unsigned int)h16(gx) << 16;   // col 15 = high half of word 7
            pk1[7] = (unsigned int)h16(gy) << 16;
            // recurrence downward: g[t] = r*(g[t+1]+P(t+1)) - r^60*P(t+60)
            #pragma unroll
            for (int c = 14; c >= 0; --c) {
                const int t = ts + c;
                float2 p1  = ldP2(pb, t + 1,  q0);
                float2 p60 = ldP2(pb, t + 60, q0);
                gx = r * (gx + p1.x) - r60 * p60.x;
                gy = r * (gy + p1.y) - r60 * p60.y;
                psx += p1.x; psy += p1.y;
                if (c & 1) {
                    pk0[c >> 1] = (unsigned int)h16(gx) << 16;
                    pk1[c >> 1] = (unsigned int)h16(gy) << 16;
                } else {
                    pk0[c >> 1] |= h16(gx);
                    pk1[c >> 1] |= h16(gy);
                }
            }
            unsigned short* d0 = &g_lds[q0 * 72 + wv * 16];
            *(uint4*)d0       = make_uint4(pk0[0], pk0[1], pk0[2], pk0[3]);
            *(uint4*)(d0 + 8) = make_uint4(pk0[4], pk0[5], pk0[6], pk0[7]);
            unsigned short* d1 = &g_lds[(q0 + 1) * 72 + wv * 16];
            *(uint4*)d1       = make_uint4(pk1[0], pk1[1], pk1[2], pk1[3]);
            *(uint4*)(d1 + 8) = make_uint4(pk1[4], pk1[5], pk1[6], pk1[7]);
        }
        __syncthreads();
        // ---------- MFMA phase: S += pre_chunk^T @ g_chunk (K = 64) ----------
        #pragma unroll
        for (int ks = 0; ks < 2; ++ks) {
            const int trow = tc + ks * 32 + (lane >> 4) * 8;  // A rows this lane covers
            f16x8 af[2];
            #pragma unroll
            for (int i = 0; i < 2; ++i) {
                const int pcol = wv * 32 + i * 16 + (lane & 15);
                const float* src = ab + (size_t)trow * NN + pcol;
                #pragma unroll
                for (int j = 0; j < 8; ++j)
                    af[i][j] = (_Float16)src[(size_t)j * NN];   // 0/1 exact in fp16
            }
            const int koff = ks * 32 + (lane >> 4) * 8;
            #pragma unroll
            for (int qt = 0; qt < 8; ++qt) {
                const f16x8 bf = *(const f16x8*)&g_lds[(qt * 16 + (lane & 15)) * 72 + koff];
                acc[0][qt] = __builtin_amdgcn_mfma_f32_16x16x32_f16(af[0], bf, acc[0][qt], 0, 0, 0);
                acc[1][qt] = __builtin_amdgcn_mfma_f32_16x16x32_f16(af[1], bf, acc[1][qt], 0, 0, 0);
            }
        }
        __syncthreads();
    }

    // ---------- write partial S (fp16; max |S_partial| < 5000, safe) ----------
    #pragma unroll
    for (int i = 0; i < 2; ++i)
        #pragma unroll
        for (int qt = 0; qt < 8; ++qt)
            #pragma unroll
            for (int rg = 0; rg < 4; ++rg) {
                const int prow = wv * 32 + i * 16 + (lane >> 4) * 4 + rg;
                const int qcol = qt * 16 + (lane & 15);
                const float v = acc[i][qt][rg];
                if constexpr (ATOMIC) atomicAdd(&outat[prow * NN + qcol], v);
                else part[(size_t)blk * OUTN + prow * NN + qcol] = (_Float16)v;
            }

    // ---------- post column sums for homeostatic term ----------
    lds_ps[wv][q0]     = psx;
    lds_ps[wv][q0 + 1] = psy;
    __syncthreads();
    if (tid < NN) {
        float s = lds_ps[0][tid] + lds_ps[1][tid] + lds_ps[2][tid] + lds_ps[3][tid];
        if (chunk == 0) s += pb[tid];    // window (t0,t0+256] misses t=0 row once per batch
        if constexpr (ATOMIC) atomicAdd(&wpost[tid], s);
        else wpost[blk * NN + tid] = s;
    }
}

// 1 block x 128 threads: hfac[q] = -1e-3 * alpha * (mean_post[q] - 0.1)
__global__ void hfac_kernel(const float* __restrict__ wpost, const int* __restrict__ dtp,
                            float* __restrict__ hfac, int nb)
{
    const int q = threadIdx.x;
    float s = 0.f;
    for (int k = 0; k < nb; ++k) s += wpost[k * NN + q];
    const float dtf   = (float)(*dtp);
    const float alpha = dtf * 1e-3f;
    const float mean  = s * (1.0f / (float)(BB * TT));
    hfac[q] = -0.001f * (alpha * (mean - 0.1f));
}

// split-K reduce over 512 fp16 partials + epilogue. grid 128 x 256.
__global__ __launch_bounds__(256)
void finalize_ws(const _Float16* __restrict__ part, const float* __restrict__ hfac,
                 const float* __restrict__ W, float* __restrict__ out)
{
    __shared__ float2 red[4][64];
    const int pr = threadIdx.x & 63;
    const int kq = threadIdx.x >> 6;
    const int i2 = blockIdx.x * 64 + pr;            // element-pair index
    const f16x2* p2 = (const f16x2*)part;
    float sx = 0.f, sy = 0.f;
    #pragma unroll 8
    for (int k = kq * (NBLK / 4); k < (kq + 1) * (NBLK / 4); ++k) {
        f16x2 h = p2[(size_t)k * (OUTN / 2) + i2];
        sx += (float)h[0];
        sy += (float)h[1];
    }
    red[kq][pr] = make_float2(sx, sy);
    __syncthreads();
    if (threadIdx.x < 64) {
        float2 a = red[0][pr], b2 = red[1][pr], c = red[2][pr], d = red[3][pr];
        sx = a.x + b2.x + c.x + d.x;
        sy = a.y + b2.y + c.y + d.y;
        const int i = i2 * 2;
        const int q = i & 127;
        const float scale = (float)((0.005 - 0.00525) / (double)(BB * TT));
        float2 w = *(const float2*)(W + i);
        float2 o;
        o.x = fmaf(sx, scale, hfac[q] * w.x);
        o.y = fmaf(sy, scale, hfac[q + 1] * w.y);
        *(float2*)(out + i) = o;
    }
}

// fallback epilogue when S was atomically accumulated in d_out
__global__ void finalize_at(const float* __restrict__ hfac, const float* __restrict__ W,
                            float* __restrict__ out)
{
    const int i = (blockIdx.x * 256 + threadIdx.x) * 2;
    const int q = i & 127;
    const float scale = (float)((0.005 - 0.00525) / (double)(BB * TT));
    float2 s = *(const float2*)(out + i);
    float2 w = *(const float2*)(W + i);
    float2 o;
    o.x = fmaf(s.x, scale, hfac[q] * w.x);
    o.y = fmaf(s.y, scale, hfac[q + 1] * w.y);
    *(float2*)(out + i) = o;
}

extern "C" void kernel_launch(void* const* d_in, const int* in_sizes, int n_in,
                              void* d_out, int out_size, void* d_ws, size_t ws_size,
                              hipStream_t stream)
{
    const float* pre  = (const float*)d_in[0];
    const float* post = (const float*)d_in[1];
    const float* W    = (const float*)d_in[2];
    const int*   dtp  = (const int*)d_in[3];
    float* out = (float*)d_out;

    const size_t part_bytes  = (size_t)NBLK * OUTN * sizeof(_Float16); // 16 MiB
    const size_t wpost_bytes = (size_t)NBLK * NN * sizeof(float);      // 256 KiB
    const size_t need = part_bytes + wpost_bytes + NN * sizeof(float);

    if (ws_size >= need) {
        _Float16* part = (_Float16*)d_ws;
        float* wpost = (float*)((char*)d_ws + part_bytes);
        float* hfac  = (float*)((char*)d_ws + part_bytes + wpost_bytes);
        hipLaunchKernelGGL((stdp_main<false>), dim3(NBLK), dim3(256), 0, stream,
                           pre, post, dtp, part, wpost, (float*)nullptr);
        hipLaunchKernelGGL(hfac_kernel, dim3(1), dim3(NN), 0, stream, wpost, dtp, hfac, NBLK);
        hipLaunchKernelGGL(finalize_ws, dim3(OUTN / 128), dim3(256), 0, stream, part, hfac, W, out);
    } else {
        // atomic fallback: needs only 1 KiB of workspace
        float* wpost = (float*)d_ws;
        float* hfac  = wpost + NN;
        hipMemsetAsync(d_out, 0, OUTN * sizeof(float), stream);
        hipMemsetAsync(wpost, 0, NN * sizeof(float), stream);
        hipLaunchKernelGGL((stdp_main<true>), dim3(NBLK), dim3(256), 0, stream,
                           pre, post, dtp, (_Float16*)nullptr, wpost, out);
        hipLaunchKernelGGL(hfac_kernel, dim3(1), dim3(NN), 0, stream, wpost, dtp, hfac, 1);
        hipLaunchKernelGGL(finalize_at, dim3(OUTN / 512), dim3(256), 0, stream, hfac, W, out);
    }
}

// Round 2
// 262.730 us; speedup vs baseline: 1.2819x; 1.2819x over previous
//
#include <hip/hip_runtime.h>

#define BB 16
#define TT 8192
#define NN 128                     // N_PRE == N_POST
constexpr int CHUNK = 256;         // time-steps per block
constexpr int NBLK  = BB * TT / CHUNK;   // 512 blocks
constexpr int OUTN  = NN * NN;           // 16384

typedef _Float16 f16x8 __attribute__((ext_vector_type(8)));
typedef _Float16 f16x2 __attribute__((ext_vector_type(2)));
typedef float    f32x4 __attribute__((ext_vector_type(4)));

__device__ __forceinline__ unsigned short h16(float x) {
    _Float16 h = (_Float16)x;
    return __builtin_bit_cast(unsigned short, h);
}

__device__ __forceinline__ float2 ldP2(const float* __restrict__ pb, int t, int q) {
    float2 v = make_float2(0.f, 0.f);
    if (t < TT) v = *(const float2*)(pb + (size_t)t * NN + q);
    return v;
}

// dump one lane's filtered columns (q0, q0+1) x 64 steps into a 64-col LDS buffer
__device__ __forceinline__ void dumpg(unsigned short* dst, int q0,
                                      const unsigned int* pk0, const unsigned int* pk1) {
    unsigned short* d0 = dst + q0 * 72;
    unsigned short* d1 = dst + (q0 + 1) * 72;
    #pragma unroll
    for (int s = 0; s < 8; ++s) {
        *(uint4*)(d0 + 8 * s) = make_uint4(pk0[4*s], pk0[4*s+1], pk0[4*s+2], pk0[4*s+3]);
        *(uint4*)(d1 + 8 * s) = make_uint4(pk1[4*s], pk1[4*s+1], pk1[4*s+2], pk1[4*s+3]);
    }
}

// grid 512 x 256 threads. Block = one 256-step chunk of one batch.
// Wave wv filters sub-chunk wv (64 steps) ONCE into registers, then
// double-buffered LDS dumps overlap with the 4 MFMA sub-phases.
template<bool ATOMIC>
__global__ __launch_bounds__(256, 2)
void stdp_main(const float* __restrict__ pre, const float* __restrict__ post,
               const int* __restrict__ dtp,
               _Float16* __restrict__ part, float* __restrict__ wpost,
               float* __restrict__ outat)
{
    __shared__ __align__(16) unsigned short g_lds[2][NN * 72]; // [buf][q][72] f16, 144B rows
    __shared__ float lds_ps[4][NN];

    const int tid   = threadIdx.x;
    const int blk   = blockIdx.x;
    const int b     = blk >> 5;          // 16 batches
    const int chunk = blk & 31;          // 32 chunks per batch
    const int t0    = chunk * CHUNK;
    const int wv    = tid >> 6;          // wave 0..3
    const int lane  = tid & 63;

    const float dtf = (float)(*dtp);
    const float r   = expf(-dtf * (1.0f / 20.0f));

    const float* pb = post + (size_t)b * TT * NN;
    const float* ab = pre  + (size_t)b * TT * NN;

    const int q0 = lane * 2;             // filter q-pair owned by this lane
    const int ts = t0 + wv * 64;         // this wave's 64-step window
    float psx = 0.f, psy = 0.f;          // post sums over (ts, ts+64]

    // ---------- filter phase: one 59-tap init + 63 recurrence steps ----------
    unsigned int pk0[32], pk1[32];
    {
        const int thi = ts + 63;
        float2 p  = ldP2(pb, thi + 1, q0);
        float wt  = r;
        float gx = r * p.x, gy = r * p.y;
        psx += p.x; psy += p.y;
        #pragma unroll
        for (int tau = 2; tau <= 59; ++tau) {
            wt *= r;
            p = ldP2(pb, thi + tau, q0);
            gx = fmaf(wt, p.x, gx);
            gy = fmaf(wt, p.y, gy);
        }
        const float r60 = wt * r;        // r^60, consistent with chained weights
        pk0[31] = (unsigned int)h16(gx) << 16;   // col 63 = high half of word 31
        pk1[31] = (unsigned int)h16(gy) << 16;
        // recurrence downward: g[t] = r*(g[t+1]+P(t+1)) - r^60*P(t+60)
        #pragma unroll
        for (int c = 62; c >= 0; --c) {
            float2 p1  = ldP2(pb, ts + c + 1,  q0);
            float2 p60 = ldP2(pb, ts + c + 60, q0);
            gx = r * (gx + p1.x) - r60 * p60.x;
            gy = r * (gy + p1.y) - r60 * p60.y;
            psx += p1.x; psy += p1.y;
            if (c & 1) {
                pk0[c >> 1] = (unsigned int)h16(gx) << 16;
                pk1[c >> 1] = (unsigned int)h16(gy) << 16;
            } else {
                pk0[c >> 1] |= h16(gx);
                pk1[c >> 1] |= h16(gy);
            }
        }
    }

    f32x4 acc[2][8];
    #pragma unroll
    for (int i = 0; i < 2; ++i)
        #pragma unroll
        for (int j = 0; j < 8; ++j)
            acc[i][j] = (f32x4){0.f, 0.f, 0.f, 0.f};

    if (wv == 0) dumpg(g_lds[0], q0, pk0, pk1);
    __syncthreads();

    // ---------- MFMA phases: S += pre_sub^T @ g_sub, double-buffered ----------
    #pragma unroll
    for (int sc = 0; sc < 4; ++sc) {
        if (wv == sc + 1) dumpg(g_lds[(sc + 1) & 1], q0, pk0, pk1);
        const unsigned short* gb = g_lds[sc & 1];
        const int tc = t0 + sc * 64;
        #pragma unroll
        for (int ks = 0; ks < 2; ++ks) {
            const int trow = tc + ks * 32 + (lane >> 4) * 8;  // A K-rows this lane covers
            f16x8 af[2];
            #pragma unroll
            for (int i = 0; i < 2; ++i) {
                const int pcol = wv * 32 + i * 16 + (lane & 15);
                const float* src = ab + (size_t)trow * NN + pcol;
                #pragma unroll
                for (int j = 0; j < 8; ++j)
                    af[i][j] = (_Float16)src[(size_t)j * NN];   // 0/1 exact in fp16
            }
            const int koff = ks * 32 + (lane >> 4) * 8;
            #pragma unroll
            for (int qt = 0; qt < 8; ++qt) {
                const f16x8 bf = *(const f16x8*)&gb[(qt * 16 + (lane & 15)) * 72 + koff];
                acc[0][qt] = __builtin_amdgcn_mfma_f32_16x16x32_f16(af[0], bf, acc[0][qt], 0, 0, 0);
                acc[1][qt] = __builtin_amdgcn_mfma_f32_16x16x32_f16(af[1], bf, acc[1][qt], 0, 0, 0);
            }
        }
        __syncthreads();
    }

    // ---------- write partial S (fp16; max |S_partial| < 5000, safe) ----------
    #pragma unroll
    for (int i = 0; i < 2; ++i)
        #pragma unroll
        for (int qt = 0; qt < 8; ++qt)
            #pragma unroll
            for (int rg = 0; rg < 4; ++rg) {
                const int prow = wv * 32 + i * 16 + (lane >> 4) * 4 + rg;
                const int qcol = qt * 16 + (lane & 15);
                const float v = acc[i][qt][rg];
                if constexpr (ATOMIC) atomicAdd(&outat[prow * NN + qcol], v);
                else part[(size_t)blk * OUTN + prow * NN + qcol] = (_Float16)v;
            }

    // ---------- post column sums for homeostatic term ----------
    lds_ps[wv][q0]     = psx;
    lds_ps[wv][q0 + 1] = psy;
    __syncthreads();
    if (tid < NN) {
        float s = lds_ps[0][tid] + lds_ps[1][tid] + lds_ps[2][tid] + lds_ps[3][tid];
        if (chunk == 0) s += pb[tid];    // window (t0,t0+256] misses t=0 row once per batch
        if constexpr (ATOMIC) atomicAdd(&wpost[tid], s);
        else wpost[(size_t)tid * NBLK + blk] = s;   // transposed: [q][NBLK] for coalesced reduce
    }
}

// 128 blocks x 64 threads: block q reduces its 512 partial sums (coalesced), shfl tree.
__global__ void hfac_kernel(const float* __restrict__ wpost, const int* __restrict__ dtp,
                            float* __restrict__ hfac, int nb)
{
    const int q = blockIdx.x;
    float s = 0.f;
    for (int k = threadIdx.x; k < nb; k += 64) s += wpost[(size_t)q * nb + k];
    #pragma unroll
    for (int off = 32; off; off >>= 1) s += __shfl_down(s, off, 64);
    if (threadIdx.x == 0) {
        const float dtf   = (float)(*dtp);
        const float alpha = dtf * 1e-3f;
        const float mean  = s * (1.0f / (float)(BB * TT));
        hfac[q] = -0.001f * (alpha * (mean - 0.1f));
    }
}

// split-K reduce over 512 fp16 partials + epilogue. grid 128 x 256.
__global__ __launch_bounds__(256)
void finalize_ws(const _Float16* __restrict__ part, const float* __restrict__ hfac,
                 const float* __restrict__ W, float* __restrict__ out)
{
    __shared__ float2 red[4][64];
    const int pr = threadIdx.x & 63;
    const int kq = threadIdx.x >> 6;
    const int i2 = blockIdx.x * 64 + pr;            // element-pair index
    const f16x2* p2 = (const f16x2*)part;
    float sx = 0.f, sy = 0.f;
    #pragma unroll 8
    for (int k = kq * (NBLK / 4); k < (kq + 1) * (NBLK / 4); ++k) {
        f16x2 h = p2[(size_t)k * (OUTN / 2) + i2];
        sx += (float)h[0];
        sy += (float)h[1];
    }
    red[kq][pr] = make_float2(sx, sy);
    __syncthreads();
    if (threadIdx.x < 64) {
        float2 a = red[0][pr], b2 = red[1][pr], c = red[2][pr], d = red[3][pr];
        sx = a.x + b2.x + c.x + d.x;
        sy = a.y + b2.y + c.y + d.y;
        const int i = i2 * 2;
        const int q = i & 127;
        const float scale = (float)((0.005 - 0.00525) / (double)(BB * TT));
        float2 w = *(const float2*)(W + i);
        float2 o;
        o.x = fmaf(sx, scale, hfac[q] * w.x);
        o.y = fmaf(sy, scale, hfac[q + 1] * w.y);
        *(float2*)(out + i) = o;
    }
}

// fallback epilogue when S was atomically accumulated in d_out
__global__ void finalize_at(const float* __restrict__ hfac, const float* __restrict__ W,
                            float* __restrict__ out)
{
    const int i = (blockIdx.x * 256 + threadIdx.x) * 2;
    const int q = i & 127;
    const float scale = (float)((0.005 - 0.00525) / (double)(BB * TT));
    float2 s = *(const float2*)(out + i);
    float2 w = *(const float2*)(W + i);
    float2 o;
    o.x = fmaf(s.x, scale, hfac[q] * w.x);
    o.y = fmaf(s.y, scale, hfac[q + 1] * w.y);
    *(float2*)(out + i) = o;
}

extern "C" void kernel_launch(void* const* d_in, const int* in_sizes, int n_in,
                              void* d_out, int out_size, void* d_ws, size_t ws_size,
                              hipStream_t stream)
{
    const float* pre  = (const float*)d_in[0];
    const float* post = (const float*)d_in[1];
    const float* W    = (const float*)d_in[2];
    const int*   dtp  = (const int*)d_in[3];
    float* out = (float*)d_out;

    const size_t part_bytes  = (size_t)NBLK * OUTN * sizeof(_Float16); // 16 MiB
    const size_t wpost_bytes = (size_t)NBLK * NN * sizeof(float);      // 256 KiB
    const size_t need = part_bytes + wpost_bytes + NN * sizeof(float);

    if (ws_size >= need) {
        _Float16* part = (_Float16*)d_ws;
        float* wpost = (float*)((char*)d_ws + part_bytes);
        float* hfac  = (float*)((char*)d_ws + part_bytes + wpost_bytes);
        hipLaunchKernelGGL((stdp_main<false>), dim3(NBLK), dim3(256), 0, stream,
                           pre, post, dtp, part, wpost, (float*)nullptr);
        hipLaunchKernelGGL(hfac_kernel, dim3(NN), dim3(64), 0, stream, wpost, dtp, hfac, NBLK);
        hipLaunchKernelGGL(finalize_ws, dim3(OUTN / 128), dim3(256), 0, stream, part, hfac, W, out);
    } else {
        // atomic fallback: needs only 1 KiB of workspace
        float* wpost = (float*)d_ws;
        float* hfac  = wpost + NN;
        hipMemsetAsync(d_out, 0, OUTN * sizeof(float), stream);
        hipMemsetAsync(wpost, 0, NN * sizeof(float), stream);
        hipLaunchKernelGGL((stdp_main<true>), dim3(NBLK), dim3(256), 0, stream,
                           pre, post, dtp, (_Float16*)nullptr, wpost, out);
        hipLaunchKernelGGL(hfac_kernel, dim3(NN), dim3(64), 0, stream, wpost, dtp, hfac, 1);
        hipLaunchKernelGGL(finalize_at, dim3(OUTN / 512), dim3(256), 0, stream, hfac, W, out);
    }
}